// Round 13
// baseline (513.095 us; speedup 1.0000x reference)
//
#include <hip/hip_runtime.h>

#define NA_ 131072
#define NN  262144
#define EE  1048576
#define RR  4
#define EPS_ 1e-5f

typedef unsigned short ushort_t;
typedef unsigned char uchar_t;
typedef unsigned int uint_t;
typedef __attribute__((ext_vector_type(8))) short bf16x8;
typedef __attribute__((ext_vector_type(4))) float f32x4;

__device__ __forceinline__ float bf2f(uint_t u16) {
    return __uint_as_float(u16 << 16);
}
__device__ __forceinline__ uint_t f2bf(float f) {
    uint_t x = __float_as_uint(f);
    return (x + 0x7fffu + ((x >> 16) & 1u)) >> 16;   // RNE
}

// async global->LDS DMA, 16 B per lane; LDS dest is base + lane*16 (wave-
// uniform base), but the SOURCE address is per-lane -> swizzle lives there.
__device__ __forceinline__ void gl2lds16(const void* g, void* l) {
    __builtin_amdgcn_global_load_lds(
        (const __attribute__((address_space(1))) void*)g,
        (__attribute__((address_space(3))) void*)l, 16, 0, 0);
}

// ---------------------------------------------------------------------------
// Merged input projection. C staged through LDS -> full-line uint4 stores
// (r25-verified: WRITE inflation 1.95x removed, kernel left top-5).
// ---------------------------------------------------------------------------
__global__ __launch_bounds__(256) void proj_gemm2(const float* __restrict__ Aa,
                                                  const float* __restrict__ Aw,
                                                  const short* __restrict__ Bta,
                                                  const short* __restrict__ Btw,
                                                  const float* __restrict__ ba,
                                                  const float* __restrict__ bw,
                                                  ushort_t* __restrict__ C) {
    const int K = 64;
    __shared__ __align__(16) short smem[2 * 128 * (K + 8)];   // 36864 B
    short (*As)[K + 8] = (short (*)[K + 8])smem;
    short (*Bs)[K + 8] = (short (*)[K + 8])(smem + 128 * (K + 8));

    const bool second = blockIdx.x >= (NA_ / 128);
    const float* A      = second ? Aw : Aa;
    const short* Btg    = second ? Btw : Bta;
    const float* bias   = second ? bw : ba;
    ushort_t* Cb        = C + (second ? (size_t)NA_ * 128 : 0);
    const int bidx      = second ? blockIdx.x - NA_ / 128 : blockIdx.x;

    const int tid  = threadIdx.x;
    const int lane = tid & 63;
    const int l15  = lane & 15;
    const int q    = lane >> 4;
    const int wv   = tid >> 6;
    const int wr   = (wv >> 1) * 64;
    const int wc   = (wv & 1) * 64;
    const size_t blockRow = (size_t)bidx * 128;

    #pragma unroll
    for (int it = 0; it < 4; it++) {
        int sidx = (it * 256 + tid) * 8;
        int row = sidx / K, col = sidx % K;
        const float* Ag = A + (blockRow + row) * K + col;
        float4 v0 = *(const float4*)Ag;
        float4 v1 = *(const float4*)(Ag + 4);
        uint4 u;
        u.x = f2bf(v0.x) | (f2bf(v0.y) << 16);
        u.y = f2bf(v0.z) | (f2bf(v0.w) << 16);
        u.z = f2bf(v1.x) | (f2bf(v1.y) << 16);
        u.w = f2bf(v1.z) | (f2bf(v1.w) << 16);
        *(uint4*)&As[row][col] = u;
        *(uint4*)&Bs[row][col] = *(const uint4*)(Btg + (size_t)row * K + col);
    }
    __syncthreads();

    f32x4 acc[4][4];
    #pragma unroll
    for (int i = 0; i < 4; i++)
        #pragma unroll
        for (int j = 0; j < 4; j++) {
            acc[i][j][0] = 0.f; acc[i][j][1] = 0.f;
            acc[i][j][2] = 0.f; acc[i][j][3] = 0.f;
        }

    #pragma unroll
    for (int kk = 0; kk < 2; kk++) {
        bf16x8 af[4], bfr[4];
        #pragma unroll
        for (int i = 0; i < 4; i++)
            af[i] = *(const bf16x8*)&As[wr + i * 16 + l15][kk * 32 + q * 8];
        #pragma unroll
        for (int j = 0; j < 4; j++)
            bfr[j] = *(const bf16x8*)&Bs[wc + j * 16 + l15][kk * 32 + q * 8];
        #pragma unroll
        for (int i = 0; i < 4; i++)
            #pragma unroll
            for (int j = 0; j < 4; j++)
                acc[i][j] = __builtin_amdgcn_mfma_f32_16x16x32_bf16(
                    af[i], bfr[j], acc[i][j], 0, 0, 0);
    }

    // ---- C-stage: bf16 results -> LDS [128][136], then full-line out ----
    __syncthreads();                      // all MFMA reads of As/Bs done
    ushort_t* Cs = (ushort_t*)smem;       // 128*136*2 = 34816 B <= 36864
    #pragma unroll
    for (int j = 0; j < 4; j++) {
        int col = wc + j * 16 + l15;
        float bv = bias[col];
        #pragma unroll
        for (int i = 0; i < 4; i++) {
            int rbase = wr + i * 16 + q * 4;
            #pragma unroll
            for (int r = 0; r < 4; r++) {
                float v = fmaxf(acc[i][j][r] + bv, 0.f);
                Cs[(rbase + r) * 136 + col] = (ushort_t)f2bf(v);
            }
        }
    }
    __syncthreads();
    #pragma unroll
    for (int k = 0; k < 8; k++) {
        int c = k * 256 + tid;            // 0..2047 uint4 chunks
        int row = c >> 4, seg = c & 15;
        uint4 v = *(const uint4*)&Cs[row * 136 + seg * 8];
        *(uint4*)&Cb[(blockRow + row) * 128 + seg * 8] = v;
    }
}

// ---------------------------------------------------------------------------
// Weight prep.
// ---------------------------------------------------------------------------
__global__ void prep_weights(const float* __restrict__ Wia,
                             const float* __restrict__ Wiw,
                             const float* __restrict__ Wroot,
                             const float* __restrict__ Wrel,
                             short* __restrict__ wt) {
    int e = blockIdx.x * 256 + threadIdx.x;
    if (e < 8192) {
        int k = e >> 7, n = e & 127;
        wt[n * 64 + k] = (short)f2bf(Wia[e]);
    } else if (e < 16384) {
        int t = e - 8192;
        int k = t >> 7, n = t & 127;
        wt[8192 + n * 64 + k] = (short)f2bf(Wiw[t]);
    } else {
        int t = e - 16384;           // 0 .. 163839
        int l = t / 81920;
        int d = t % 81920;
        int kc = d / 16384;
        int rem2 = d % 16384;
        int n = rem2 >> 7;
        int kkk = rem2 & 127;
        float val = (kc < 4)
            ? Wrel[(((size_t)l * 4 + kc) * 128 + kkk) * 128 + n]
            : Wroot[((size_t)l * 128 + kkk) * 128 + n];
        wt[16384 + (size_t)l * 81920 + kc * 16384 + n * 128 + kkk] =
            (short)f2bf(val);
    }
}

// ---------------------------------------------------------------------------
// CSR count. Padded counters, one node per 64 B line (r18-verified win).
// ---------------------------------------------------------------------------
__global__ void count_edges(const int* __restrict__ dstv,
                            const int* __restrict__ et,
                            uint_t* __restrict__ cntp,
                            uchar_t* __restrict__ rank) {
    int base = blockIdx.x * 1024 + threadIdx.x;
    int e0 = base, e1 = base + 256, e2 = base + 512, e3 = base + 768;
    int r0 = et[e0], r1 = et[e1], r2 = et[e2], r3 = et[e3];
    int d0 = dstv[e0], d1 = dstv[e1], d2 = dstv[e2], d3 = dstv[e3];
    uint_t o0 = atomicAdd(&cntp[(size_t)d0 * 16], 1u << (8 * r0));
    uint_t o1 = atomicAdd(&cntp[(size_t)d1 * 16], 1u << (8 * r1));
    uint_t o2 = atomicAdd(&cntp[(size_t)d2 * 16], 1u << (8 * r2));
    uint_t o3 = atomicAdd(&cntp[(size_t)d3 * 16], 1u << (8 * r3));
    rank[e0] = (uchar_t)((o0 >> (8 * r0)) & 0xffu);
    rank[e1] = (uchar_t)((o1 >> (8 * r1)) & 0xffu);
    rank[e2] = (uchar_t)((o2 >> (8 * r2)) & 0xffu);
    rank[e3] = (uchar_t)((o3 >> (8 * r3)) & 0xffu);
}

// ---------------------------------------------------------------------------
// inv_deg + scan1 merged (register deg; r24-verified).
// ---------------------------------------------------------------------------
__global__ __launch_bounds__(256) void inv_scan1(
    const uint_t* __restrict__ cntp,
    float* __restrict__ inv,
    uint_t* __restrict__ prefd,
    int* __restrict__ offs,
    int* __restrict__ bsum) {
    __shared__ int lds[256];
    const int tid = threadIdx.x;
    const int bid = blockIdx.x;
    const int gt  = bid * 256 + tid;

    uint_t c = cntp[(size_t)gt * 16];
    int c0 = c & 255, c1 = (c >> 8) & 255, c2 = (c >> 16) & 255, c3 = c >> 24;
    float4 w;
    w.x = 1.0f / (float)(c0 > 1 ? c0 : 1);
    w.y = 1.0f / (float)(c1 > 1 ? c1 : 1);
    w.z = 1.0f / (float)(c2 > 1 ? c2 : 1);
    w.w = 1.0f / (float)(c3 > 1 ? c3 : 1);
    ((float4*)inv)[gt] = w;
    const int mydeg = c0 + c1 + c2 + c3;
    prefd[gt] = ((uint_t)c0 << 8) | ((uint_t)(c0 + c1) << 16)
              | ((uint_t)(c0 + c1 + c2) << 24);

    int incl = mydeg;
    lds[tid] = incl;
    __syncthreads();
    for (int off = 1; off < 256; off <<= 1) {
        int t = (tid >= off) ? lds[tid - off] : 0;
        __syncthreads();
        incl += t;
        lds[tid] = incl;
        __syncthreads();
    }
    offs[gt] = incl - mydeg;
    if (tid == 255) bsum[bid] = incl;
}

__global__ void scan_bsum(int* __restrict__ bsum) {
    __shared__ int lds[256];
    int tid = threadIdx.x;
    int t0 = bsum[tid * 4 + 0], t1 = bsum[tid * 4 + 1];
    int t2 = bsum[tid * 4 + 2], t3 = bsum[tid * 4 + 3];
    int s = t0 + t1 + t2 + t3;
    int incl = s;
    lds[tid] = incl;
    __syncthreads();
    for (int off = 1; off < 256; off <<= 1) {
        int t = (tid >= off) ? lds[tid - off] : 0;
        __syncthreads();
        incl += t;
        lds[tid] = incl;
        __syncthreads();
    }
    int e = incl - s;
    bsum[tid * 4 + 0] = e;
    bsum[tid * 4 + 1] = e + t0;
    bsum[tid * 4 + 2] = e + t0 + t1;
    bsum[tid * 4 + 3] = e + t0 + t1 + t2;
}

__global__ void scan_add(int* __restrict__ offs, const int* __restrict__ bsum) {
    int i = blockIdx.x * 256 + threadIdx.x;
    offs[i] = offs[i] + bsum[blockIdx.x];
    if (i == 0) offs[NN] = EE;
}

__global__ void place_edges(const int* __restrict__ srcv,
                            const int* __restrict__ dstv,
                            const int* __restrict__ et,
                            const uchar_t* __restrict__ rank,
                            const int* __restrict__ offs,
                            const uint_t* __restrict__ prefd,
                            uint_t* __restrict__ pk) {
    int base = blockIdx.x * 1024 + threadIdx.x;
    #pragma unroll
    for (int t = 0; t < 4; t++) {
        int e = base + t * 256;
        int d = dstv[e], r = et[e];
        int pos = offs[d] + (int)((prefd[d] >> (8 * r)) & 255u) + (int)rank[e];
        pk[pos] = (uint_t)srcv[e] | ((uint_t)r << 18);
    }
}

// ---------------------------------------------------------------------------
// Pull aggregation: one wave per dst node — exact r17/r21 body (measured
// best). Unchanged.
// ---------------------------------------------------------------------------
__global__ __launch_bounds__(256) void agg_means(const uint_t* __restrict__ pk,
                                                 const int* __restrict__ offs,
                                                 const ushort_t* __restrict__ hold,
                                                 const float* __restrict__ inv,
                                                 ushort_t* __restrict__ M,
                                                 int lo, int rowsCap) {
    const int wv  = __builtin_amdgcn_readfirstlane(threadIdx.x >> 6);
    const int idx = blockIdx.x * 4 + wv;
    const int d   = lo + idx;
    const int lane = threadIdx.x & 63;
    const int beg = offs[d];
    const int end = offs[d + 1];
    const float4 w4 = ((const float4*)inv)[d];   // early s_load_dwordx4

    float a0x = 0.f, a0y = 0.f, a1x = 0.f, a1y = 0.f;
    float a2x = 0.f, a2y = 0.f, a3x = 0.f, a3y = 0.f;

    const uint_t* hold32 = (const uint_t*)hold;

    auto accs = [&](uint_t p, uint_t v, bool valid) {
        float x = bf2f(v & 0xffffu), y = bf2f(v >> 16);
        uint_t r = p >> 18;
        float m0 = (valid && r == 0u) ? 1.f : 0.f;
        float m1 = (valid && r == 1u) ? 1.f : 0.f;
        float m2 = (valid && r == 2u) ? 1.f : 0.f;
        float m3 = (valid && r == 3u) ? 1.f : 0.f;
        a0x += m0 * x;  a0y += m0 * y;
        a1x += m1 * x;  a1y += m1 * y;
        a2x += m2 * x;  a2y += m2 * y;
        a3x += m3 * x;  a3y += m3 * y;
    };

    for (int e = beg; e < end; e += 8) {
        const int last = end - 1;
        int a1i = (e + 1 < end) ? e + 1 : last;
        int a2i = (e + 2 < end) ? e + 2 : last;
        int a3i = (e + 3 < end) ? e + 3 : last;
        uint_t p0 = pk[e];
        uint_t p1 = pk[a1i];
        uint_t p2 = pk[a2i];
        uint_t p3 = pk[a3i];
        uint_t v0 = hold32[(size_t)(p0 & 0x3FFFFu) * 64 + lane];
        uint_t v1 = hold32[(size_t)(p1 & 0x3FFFFu) * 64 + lane];
        uint_t v2 = hold32[(size_t)(p2 & 0x3FFFFu) * 64 + lane];
        uint_t v3 = hold32[(size_t)(p3 & 0x3FFFFu) * 64 + lane];

        const bool hB = (e + 4 < end);   // wave-uniform -> scalar branch
        if (hB) {
            int b1i = (e + 5 < end) ? e + 5 : last;
            int b2i = (e + 6 < end) ? e + 6 : last;
            int b3i = (e + 7 < end) ? e + 7 : last;
            uint_t q0 = pk[e + 4];
            uint_t q1 = pk[b1i];
            uint_t q2 = pk[b2i];
            uint_t q3 = pk[b3i];
            uint_t u0 = hold32[(size_t)(q0 & 0x3FFFFu) * 64 + lane];
            uint_t u1 = hold32[(size_t)(q1 & 0x3FFFFu) * 64 + lane];
            uint_t u2 = hold32[(size_t)(q2 & 0x3FFFFu) * 64 + lane];
            uint_t u3 = hold32[(size_t)(q3 & 0x3FFFFu) * 64 + lane];
            accs(p0, v0, true);
            accs(p1, v1, true);
            accs(p2, v2, true);
            accs(p3, v3, true);
            accs(q0, u0, true);
            accs(q1, u1, e + 5 < end);
            accs(q2, u2, e + 6 < end);
            accs(q3, u3, e + 7 < end);
        } else {
            accs(p0, v0, true);
            accs(p1, v1, e + 1 < end);
            accs(p2, v2, e + 2 < end);
            accs(p3, v3, e + 3 < end);
        }
    }

    uint_t* P = (uint_t*)M;
    size_t planeU = (size_t)rowsCap * 64;
    size_t rowU = (size_t)idx * 64 + lane;
    P[rowU]              = f2bf(a0x * w4.x) | (f2bf(a0y * w4.x) << 16);
    P[planeU + rowU]     = f2bf(a1x * w4.y) | (f2bf(a1y * w4.y) << 16);
    P[2 * planeU + rowU] = f2bf(a2x * w4.z) | (f2bf(a2y * w4.z) << 16);
    P[3 * planeU + rowU] = f2bf(a3x * w4.w) | (f2bf(a3y * w4.w) << 16);
}

// ---------------------------------------------------------------------------
// Layer GEMM + LN + ReLU (+ optional fused head). hnew staged through LDS
// -> full-line stores (r25-verified). Unchanged.
// ---------------------------------------------------------------------------
template<bool HEAD>
__global__ __launch_bounds__(256) void layer_gemm_ln(
    const ushort_t* __restrict__ Mg,
    const ushort_t* __restrict__ hold,
    const short* __restrict__ Btg,       // [5][128 n][128 k] chunk-major
    const float* __restrict__ bconv,
    const float* __restrict__ lng,
    const float* __restrict__ lnb,
    ushort_t* __restrict__ hnew,
    const float* __restrict__ Wout,
    const float* __restrict__ bout,
    const float* __restrict__ basep,
    float* __restrict__ pred,
    int lo, int rowsCap) {
    __shared__ __align__(16) short As[64 * 128];       // 16 KB
    __shared__ __align__(16) short Bs[128 * 128];      // 32 KB
    __shared__ float lds_s[64][2], lds_q[64][2], lds_h[64][2];

    const int tid  = threadIdx.x;
    const int lane = tid & 63;
    const int l15  = lane & 15;
    const int q    = lane >> 4;
    const int wv   = tid >> 6;
    const int wr   = (wv >> 1) * 32;     // 2 row-bands of 32
    const int wc   = (wv & 1) * 64;      // 2 col-bands of 64
    const int blockRowL = blockIdx.x * 64;
    const size_t planeS = (size_t)rowsCap * 128;

    f32x4 acc[2][4];
    #pragma unroll
    for (int i = 0; i < 2; i++)
        #pragma unroll
        for (int j = 0; j < 4; j++) {
            acc[i][j][0] = 0.f; acc[i][j][1] = 0.f;
            acc[i][j][2] = 0.f; acc[i][j][3] = 0.f;
        }

    // per-lane source offset with XOR group swizzle (r12-verified).
    const int rloc = lane >> 4;
    const int gsw  = (lane & 15) ^ ((wv * 4 + rloc) & 15);
    const int lby  = (rloc << 8) + (gsw << 4);

    for (int kc = 0; kc < 5; kc++) {
        const char* asrc = (kc < 4)
            ? (const char*)(Mg + (size_t)kc * planeS + (size_t)blockRowL * 128)
            : (const char*)(hold + (size_t)(lo + blockRowL) * 128);
        const char* bsrc = (const char*)(Btg + (size_t)kc * 16384);
        __syncthreads();
        #pragma unroll
        for (int it = 0; it < 8; it++) {
            int off = it * 4096 + wv * 1024;
            if (it < 4) gl2lds16(asrc + off + lby, (char*)As + off);
            gl2lds16(bsrc + off + lby, (char*)Bs + off);
        }
        __syncthreads();

        #pragma unroll
        for (int kk = 0; kk < 4; kk++) {
            bf16x8 af[2], bfr[4];
            #pragma unroll
            for (int i = 0; i < 2; i++)
                af[i] = *(const bf16x8*)
                    &As[(wr + i * 16 + l15) * 128 + (((kk * 4 + q) ^ l15) << 3)];
            #pragma unroll
            for (int j = 0; j < 4; j++)
                bfr[j] = *(const bf16x8*)
                    &Bs[(wc + j * 16 + l15) * 128 + (((kk * 4 + q) ^ l15) << 3)];
            #pragma unroll
            for (int i = 0; i < 2; i++)
                #pragma unroll
                for (int j = 0; j < 4; j++)
                    acc[i][j] = __builtin_amdgcn_mfma_f32_16x16x32_bf16(
                        af[i], bfr[j], acc[i][j], 0, 0, 0);
        }
    }

    // ---- epilogue: + b_conv, LayerNorm, affine, ReLU (+ head dot) ----
    float bj[4], gj[4], bbj[4], wj[4];
    #pragma unroll
    for (int j = 0; j < 4; j++) {
        int col = wc + j * 16 + l15;
        bj[j]  = bconv[col];
        gj[j]  = lng[col];
        bbj[j] = lnb[col];
        if (HEAD) wj[j] = Wout[col];
    }
    #pragma unroll
    for (int i = 0; i < 2; i++)
        #pragma unroll
        for (int j = 0; j < 4; j++)
            #pragma unroll
            for (int r = 0; r < 4; r++) acc[i][j][r] += bj[j];

    float ps[2][4], pq[2][4];
    #pragma unroll
    for (int i = 0; i < 2; i++)
        #pragma unroll
        for (int r = 0; r < 4; r++) {
            float s = 0.f, qq = 0.f;
            #pragma unroll
            for (int j = 0; j < 4; j++) {
                float v = acc[i][j][r];
                s += v;
                qq += v * v;
            }
            ps[i][r] = s;
            pq[i][r] = qq;
        }
    #pragma unroll
    for (int m = 1; m <= 8; m <<= 1)
        #pragma unroll
        for (int i = 0; i < 2; i++)
            #pragma unroll
            for (int r = 0; r < 4; r++) {
                ps[i][r] += __shfl_xor(ps[i][r], m);
                pq[i][r] += __shfl_xor(pq[i][r], m);
            }

    if (l15 == 0) {
        #pragma unroll
        for (int i = 0; i < 2; i++)
            #pragma unroll
            for (int r = 0; r < 4; r++) {
                int row = wr + i * 16 + q * 4 + r;
                lds_s[row][wv & 1] = ps[i][r];
                lds_q[row][wv & 1] = pq[i][r];
            }
    }
    __syncthreads();   // also fences last Bs reads (K-loop done for all)

    ushort_t* Cs = (ushort_t*)Bs;        // 64*136*2 = 17408 B <= 32 KB
    float hs[2][4];
    #pragma unroll
    for (int i = 0; i < 2; i++)
        #pragma unroll
        for (int r = 0; r < 4; r++) {
            int row = wr + i * 16 + q * 4 + r;
            float sum = lds_s[row][0] + lds_s[row][1];
            float sq  = lds_q[row][0] + lds_q[row][1];
            float mu  = sum * (1.0f / 128.0f);
            float var = sq * (1.0f / 128.0f) - mu * mu;
            float rs  = rsqrtf(var + EPS_);
            float hd = 0.f;
            #pragma unroll
            for (int j = 0; j < 4; j++) {
                float v = (acc[i][j][r] - mu) * rs * gj[j] + bbj[j];
                v = fmaxf(v, 0.f);
                if (HEAD) hd += v * wj[j];
                else Cs[row * 136 + wc + j * 16 + l15] = (ushort_t)f2bf(v);
            }
            if (HEAD) hs[i][r] = hd;
        }

    if (!HEAD) {
        __syncthreads();
        #pragma unroll
        for (int k = 0; k < 4; k++) {
            int c = k * 256 + tid;        // 0..1023 uint4 chunks
            int row = c >> 4, seg = c & 15;
            uint4 v = *(const uint4*)&Cs[row * 136 + seg * 8];
            *(uint4*)&hnew[(size_t)(lo + blockRowL + row) * 128 + seg * 8] = v;
        }
    }

    if (HEAD) {
        #pragma unroll
        for (int m = 1; m <= 8; m <<= 1)
            #pragma unroll
            for (int i = 0; i < 2; i++)
                #pragma unroll
                for (int r = 0; r < 4; r++)
                    hs[i][r] += __shfl_xor(hs[i][r], m);
        if (l15 == 0) {
            #pragma unroll
            for (int i = 0; i < 2; i++)
                #pragma unroll
                for (int r = 0; r < 4; r++) {
                    int row = wr + i * 16 + q * 4 + r;
                    lds_h[row][wv & 1] = hs[i][r];
                }
        }
        __syncthreads();
        if (tid < 64)
            pred[lo + blockRowL + tid] =
                lds_h[tid][0] + lds_h[tid][1] + bout[0] + basep[0];
    }
}

// ---------------------------------------------------------------------------
extern "C" void kernel_launch(void* const* d_in, const int* in_sizes, int n_in,
                              void* d_out, int out_size, void* d_ws, size_t ws_size,
                              hipStream_t stream) {
    const float* x_a    = (const float*)d_in[0];
    const float* x_w    = (const float*)d_in[1];
    const int*   eidx   = (const int*)d_in[2];
    const int*   etype  = (const int*)d_in[3];
    const float* W_in_a = (const float*)d_in[4];
    const float* b_in_a = (const float*)d_in[5];
    const float* W_in_w = (const float*)d_in[6];
    const float* b_in_w = (const float*)d_in[7];
    const float* W_rel  = (const float*)d_in[8];
    const float* W_root = (const float*)d_in[9];
    const float* b_conv = (const float*)d_in[10];
    const float* ln_g   = (const float*)d_in[11];
    const float* ln_b   = (const float*)d_in[12];
    const float* W_out  = (const float*)d_in[13];
    const float* b_out  = (const float*)d_in[14];
    const float* base   = (const float*)d_in[15];

    const int* src  = eidx;
    const int* dstv = eidx + EE;

    // ---- workspace: hA placed LAST among persistents so layer-1's M can
    //      overlay [hA .. end] (hA is dead in layer 1). Layer-0's M uses
    //      [scratch .. end]. ----
    char* p = (char*)d_ws;
    auto alloc = [&](size_t bytes) {
        char* q = p;
        p += (bytes + 255) & ~(size_t)255;
        return q;
    };
    ushort_t* hB   = (ushort_t*)alloc((size_t)NN * 128 * 2);   // 67.1 MB
    float*    inv  = (float*)alloc((size_t)RR * NN * 4);       // 4.2 MB
    uint_t*   pk   = (uint_t*)alloc((size_t)EE * 4);           // 4.2 MB
    int*      offs = (int*)alloc((size_t)(NN + 1) * 4);        // 1.05 MB
    short*    wbuf = (short*)alloc((size_t)180224 * 2);        // 0.36 MB
    char*     hA_region = p;
    ushort_t* hA   = (ushort_t*)alloc((size_t)NN * 128 * 2);   // 67.1 MB
    char*     scratch = p;                                     // CSR tmp / M0
    uint_t*   cntp  = (uint_t*)alloc((size_t)NN * 64);         // padded, dead after CSR
    uchar_t*  rank  = (uchar_t*)alloc((size_t)EE);             // dead after CSR
    uint_t*   prefd = (uint_t*)alloc((size_t)NN * 4);          // dead after CSR
    int*      bsum  = (int*)alloc((size_t)1024 * 4);           // dead after CSR

    // r26: clamp chunk so the reused M buffer (1 KB/row) fits in the 256 MB
    // L3 alongside hold (67 MB) + the hnew chunk. At 65536 rows M = 67 MB;
    // per-chunk working set ~172 MB -> M round-trip should be L3-absorbed
    // (r25 counters: 131072-row chunks -> M 134 MB spilled fully, WRITE_SIZE
    // = 131072 KB per agg dispatch = every M byte to HBM).
    size_t rem0 = (ws_size > (size_t)(scratch - (char*)d_ws))
                      ? (ws_size - (size_t)(scratch - (char*)d_ws)) : 0;
    int cap0 = (int)(rem0 / 1024);            // 1024 B per row (4 planes)
    if (cap0 > NN) cap0 = NN;
    cap0 &= ~127;
    if (cap0 == 0) cap0 = 128;
    if (cap0 > 65536) cap0 = 65536;
    size_t rem1 = (ws_size > (size_t)(hA_region - (char*)d_ws))
                      ? (ws_size - (size_t)(hA_region - (char*)d_ws)) : 0;
    int cap1 = (int)(rem1 / 1024);
    if (cap1 > NA_) cap1 = NA_;
    cap1 &= ~127;
    if (cap1 == 0) cap1 = 128;
    if (cap1 > 65536) cap1 = 65536;

    short* wt_ina = wbuf;
    short* wt_inw = wbuf + 8192;
    auto wt_layer = [&](int l) { return wbuf + 16384 + (size_t)l * 81920; };

    // ---- CSR + inv: memset, count, inv+scan1, bsum scan, add, place ----
    hipMemsetAsync(cntp, 0, (size_t)NN * 64, stream);
    count_edges<<<EE / 1024, 256, 0, stream>>>(dstv, etype, cntp, rank);
    inv_scan1<<<NN / 256, 256, 0, stream>>>(cntp, inv, prefd, offs, bsum);
    scan_bsum<<<1, 256, 0, stream>>>(bsum);
    scan_add<<<NN / 256, 256, 0, stream>>>(offs, bsum);
    place_edges<<<EE / 1024, 256, 0, stream>>>(src, dstv, etype, rank, offs,
                                               prefd, pk);

    prep_weights<<<704, 256, 0, stream>>>(W_in_a, W_in_w, W_root, W_rel, wbuf);

    // ---- input projections: merged into one launch ----
    proj_gemm2<<<2 * (NA_ / 128), 256, 0, stream>>>(
        x_a, x_w, wt_ina, wt_inw, b_in_a, b_in_w, hA);

    // ---- layers; layer 2 only computes rows < NA and fuses the head ----
    ushort_t* hc = hA;
    ushort_t* hn = hB;
    for (int l = 0; l < 2; l++) {
        int Nout = (l == 0) ? NN : NA_;
        ushort_t* M = (l == 0) ? (ushort_t*)scratch : (ushort_t*)hA_region;
        int cap = (l == 0) ? cap0 : cap1;
        int nch = (Nout + cap - 1) / cap;
        int chunk = ((Nout / nch) + 127) & ~127;        // balanced, x128
        if (chunk > cap) chunk = cap;
        for (int lo = 0; lo < Nout; lo += chunk) {
            int cr = (Nout - lo < chunk) ? (Nout - lo) : chunk;
            agg_means<<<cr / 4, 256, 0, stream>>>(pk, offs, hc, inv, M, lo,
                                                  cap);
            if (l == 0)
                layer_gemm_ln<false><<<cr / 64, 256, 0, stream>>>(
                    M, hc, wt_layer(l), b_conv + l * 128, ln_g + l * 128,
                    ln_b + l * 128, hn, nullptr, nullptr, nullptr, nullptr,
                    lo, cap);
            else
                layer_gemm_ln<true><<<cr / 64, 256, 0, stream>>>(
                    M, hc, wt_layer(l), b_conv + l * 128, ln_g + l * 128,
                    ln_b + l * 128, nullptr, W_out, b_out, base,
                    (float*)d_out, lo, cap);
        }
        ushort_t* t = hc; hc = hn; hn = t;
    }
}

// Round 14
// 494.756 us; speedup vs baseline: 1.0371x; 1.0371x over previous
//
#include <hip/hip_runtime.h>

#define NA_ 131072
#define NN  262144
#define EE  1048576
#define RR  4
#define EPS_ 1e-5f

typedef unsigned short ushort_t;
typedef unsigned char uchar_t;
typedef unsigned int uint_t;
typedef __attribute__((ext_vector_type(8))) short bf16x8;
typedef __attribute__((ext_vector_type(4))) float f32x4;

__device__ __forceinline__ float bf2f(uint_t u16) {
    return __uint_as_float(u16 << 16);
}
__device__ __forceinline__ uint_t f2bf(float f) {
    uint_t x = __float_as_uint(f);
    return (x + 0x7fffu + ((x >> 16) & 1u)) >> 16;   // RNE
}

// async global->LDS DMA, 16 B per lane; LDS dest is base + lane*16 (wave-
// uniform base), but the SOURCE address is per-lane -> swizzle lives there.
__device__ __forceinline__ void gl2lds16(const void* g, void* l) {
    __builtin_amdgcn_global_load_lds(
        (const __attribute__((address_space(1))) void*)g,
        (__attribute__((address_space(3))) void*)l, 16, 0, 0);
}

// ---------------------------------------------------------------------------
// Merged input projection. C staged through LDS -> full-line uint4 stores
// (r25-verified: WRITE inflation 1.95x removed, kernel left top-5).
// ---------------------------------------------------------------------------
__global__ __launch_bounds__(256) void proj_gemm2(const float* __restrict__ Aa,
                                                  const float* __restrict__ Aw,
                                                  const short* __restrict__ Bta,
                                                  const short* __restrict__ Btw,
                                                  const float* __restrict__ ba,
                                                  const float* __restrict__ bw,
                                                  ushort_t* __restrict__ C) {
    const int K = 64;
    __shared__ __align__(16) short smem[2 * 128 * (K + 8)];   // 36864 B
    short (*As)[K + 8] = (short (*)[K + 8])smem;
    short (*Bs)[K + 8] = (short (*)[K + 8])(smem + 128 * (K + 8));

    const bool second = blockIdx.x >= (NA_ / 128);
    const float* A      = second ? Aw : Aa;
    const short* Btg    = second ? Btw : Bta;
    const float* bias   = second ? bw : ba;
    ushort_t* Cb        = C + (second ? (size_t)NA_ * 128 : 0);
    const int bidx      = second ? blockIdx.x - NA_ / 128 : blockIdx.x;

    const int tid  = threadIdx.x;
    const int lane = tid & 63;
    const int l15  = lane & 15;
    const int q    = lane >> 4;
    const int wv   = tid >> 6;
    const int wr   = (wv >> 1) * 64;
    const int wc   = (wv & 1) * 64;
    const size_t blockRow = (size_t)bidx * 128;

    #pragma unroll
    for (int it = 0; it < 4; it++) {
        int sidx = (it * 256 + tid) * 8;
        int row = sidx / K, col = sidx % K;
        const float* Ag = A + (blockRow + row) * K + col;
        float4 v0 = *(const float4*)Ag;
        float4 v1 = *(const float4*)(Ag + 4);
        uint4 u;
        u.x = f2bf(v0.x) | (f2bf(v0.y) << 16);
        u.y = f2bf(v0.z) | (f2bf(v0.w) << 16);
        u.z = f2bf(v1.x) | (f2bf(v1.y) << 16);
        u.w = f2bf(v1.z) | (f2bf(v1.w) << 16);
        *(uint4*)&As[row][col] = u;
        *(uint4*)&Bs[row][col] = *(const uint4*)(Btg + (size_t)row * K + col);
    }
    __syncthreads();

    f32x4 acc[4][4];
    #pragma unroll
    for (int i = 0; i < 4; i++)
        #pragma unroll
        for (int j = 0; j < 4; j++) {
            acc[i][j][0] = 0.f; acc[i][j][1] = 0.f;
            acc[i][j][2] = 0.f; acc[i][j][3] = 0.f;
        }

    #pragma unroll
    for (int kk = 0; kk < 2; kk++) {
        bf16x8 af[4], bfr[4];
        #pragma unroll
        for (int i = 0; i < 4; i++)
            af[i] = *(const bf16x8*)&As[wr + i * 16 + l15][kk * 32 + q * 8];
        #pragma unroll
        for (int j = 0; j < 4; j++)
            bfr[j] = *(const bf16x8*)&Bs[wc + j * 16 + l15][kk * 32 + q * 8];
        #pragma unroll
        for (int i = 0; i < 4; i++)
            #pragma unroll
            for (int j = 0; j < 4; j++)
                acc[i][j] = __builtin_amdgcn_mfma_f32_16x16x32_bf16(
                    af[i], bfr[j], acc[i][j], 0, 0, 0);
    }

    // ---- C-stage: bf16 results -> LDS [128][136], then full-line out ----
    __syncthreads();                      // all MFMA reads of As/Bs done
    ushort_t* Cs = (ushort_t*)smem;       // 128*136*2 = 34816 B <= 36864
    #pragma unroll
    for (int j = 0; j < 4; j++) {
        int col = wc + j * 16 + l15;
        float bv = bias[col];
        #pragma unroll
        for (int i = 0; i < 4; i++) {
            int rbase = wr + i * 16 + q * 4;
            #pragma unroll
            for (int r = 0; r < 4; r++) {
                float v = fmaxf(acc[i][j][r] + bv, 0.f);
                Cs[(rbase + r) * 136 + col] = (ushort_t)f2bf(v);
            }
        }
    }
    __syncthreads();
    #pragma unroll
    for (int k = 0; k < 8; k++) {
        int c = k * 256 + tid;            // 0..2047 uint4 chunks
        int row = c >> 4, seg = c & 15;
        uint4 v = *(const uint4*)&Cs[row * 136 + seg * 8];
        *(uint4*)&Cb[(blockRow + row) * 128 + seg * 8] = v;
    }
}

// ---------------------------------------------------------------------------
// Weight prep.
// ---------------------------------------------------------------------------
__global__ void prep_weights(const float* __restrict__ Wia,
                             const float* __restrict__ Wiw,
                             const float* __restrict__ Wroot,
                             const float* __restrict__ Wrel,
                             short* __restrict__ wt) {
    int e = blockIdx.x * 256 + threadIdx.x;
    if (e < 8192) {
        int k = e >> 7, n = e & 127;
        wt[n * 64 + k] = (short)f2bf(Wia[e]);
    } else if (e < 16384) {
        int t = e - 8192;
        int k = t >> 7, n = t & 127;
        wt[8192 + n * 64 + k] = (short)f2bf(Wiw[t]);
    } else {
        int t = e - 16384;           // 0 .. 163839
        int l = t / 81920;
        int d = t % 81920;
        int kc = d / 16384;
        int rem2 = d % 16384;
        int n = rem2 >> 7;
        int kkk = rem2 & 127;
        float val = (kc < 4)
            ? Wrel[(((size_t)l * 4 + kc) * 128 + kkk) * 128 + n]
            : Wroot[((size_t)l * 128 + kkk) * 128 + n];
        wt[16384 + (size_t)l * 81920 + kc * 16384 + n * 128 + kkk] =
            (short)f2bf(val);
    }
}

// ---------------------------------------------------------------------------
// CSR count. r27: 1 edge/thread, grid 4096 (was 4 edges/thread, grid 1024).
// Quadruples the resident-wave ceiling at identical atomic count — tests
// whether wave residency (occupancy was 29%, ceiling 50%) or in-flight
// atomic-instruction count binds this kernel. Padded counters kept.
// ---------------------------------------------------------------------------
__global__ void count_edges(const int* __restrict__ dstv,
                            const int* __restrict__ et,
                            uint_t* __restrict__ cntp,
                            uchar_t* __restrict__ rank) {
    int e = blockIdx.x * 256 + threadIdx.x;
    int r = et[e];
    int d = dstv[e];
    uint_t o = atomicAdd(&cntp[(size_t)d * 16], 1u << (8 * r));
    rank[e] = (uchar_t)((o >> (8 * r)) & 0xffu);
}

// ---------------------------------------------------------------------------
// inv_deg + scan1 merged (register deg; r24-verified).
// ---------------------------------------------------------------------------
__global__ __launch_bounds__(256) void inv_scan1(
    const uint_t* __restrict__ cntp,
    float* __restrict__ inv,
    uint_t* __restrict__ prefd,
    int* __restrict__ offs,
    int* __restrict__ bsum) {
    __shared__ int lds[256];
    const int tid = threadIdx.x;
    const int bid = blockIdx.x;
    const int gt  = bid * 256 + tid;

    uint_t c = cntp[(size_t)gt * 16];
    int c0 = c & 255, c1 = (c >> 8) & 255, c2 = (c >> 16) & 255, c3 = c >> 24;
    float4 w;
    w.x = 1.0f / (float)(c0 > 1 ? c0 : 1);
    w.y = 1.0f / (float)(c1 > 1 ? c1 : 1);
    w.z = 1.0f / (float)(c2 > 1 ? c2 : 1);
    w.w = 1.0f / (float)(c3 > 1 ? c3 : 1);
    ((float4*)inv)[gt] = w;
    const int mydeg = c0 + c1 + c2 + c3;
    prefd[gt] = ((uint_t)c0 << 8) | ((uint_t)(c0 + c1) << 16)
              | ((uint_t)(c0 + c1 + c2) << 24);

    int incl = mydeg;
    lds[tid] = incl;
    __syncthreads();
    for (int off = 1; off < 256; off <<= 1) {
        int t = (tid >= off) ? lds[tid - off] : 0;
        __syncthreads();
        incl += t;
        lds[tid] = incl;
        __syncthreads();
    }
    offs[gt] = incl - mydeg;
    if (tid == 255) bsum[bid] = incl;
}

__global__ void scan_bsum(int* __restrict__ bsum) {
    __shared__ int lds[256];
    int tid = threadIdx.x;
    int t0 = bsum[tid * 4 + 0], t1 = bsum[tid * 4 + 1];
    int t2 = bsum[tid * 4 + 2], t3 = bsum[tid * 4 + 3];
    int s = t0 + t1 + t2 + t3;
    int incl = s;
    lds[tid] = incl;
    __syncthreads();
    for (int off = 1; off < 256; off <<= 1) {
        int t = (tid >= off) ? lds[tid - off] : 0;
        __syncthreads();
        incl += t;
        lds[tid] = incl;
        __syncthreads();
    }
    int e = incl - s;
    bsum[tid * 4 + 0] = e;
    bsum[tid * 4 + 1] = e + t0;
    bsum[tid * 4 + 2] = e + t0 + t1;
    bsum[tid * 4 + 3] = e + t0 + t1 + t2;
}

__global__ void scan_add(int* __restrict__ offs, const int* __restrict__ bsum) {
    int i = blockIdx.x * 256 + threadIdx.x;
    offs[i] = offs[i] + bsum[blockIdx.x];
    if (i == 0) offs[NN] = EE;
}

__global__ void place_edges(const int* __restrict__ srcv,
                            const int* __restrict__ dstv,
                            const int* __restrict__ et,
                            const uchar_t* __restrict__ rank,
                            const int* __restrict__ offs,
                            const uint_t* __restrict__ prefd,
                            uint_t* __restrict__ pk) {
    int base = blockIdx.x * 1024 + threadIdx.x;
    #pragma unroll
    for (int t = 0; t < 4; t++) {
        int e = base + t * 256;
        int d = dstv[e], r = et[e];
        int pos = offs[d] + (int)((prefd[d] >> (8 * r)) & 255u) + (int)rank[e];
        pk[pos] = (uint_t)srcv[e] | ((uint_t)r << 18);
    }
}

// ---------------------------------------------------------------------------
// Pull aggregation: one wave per dst node — exact r17/r21 body (measured
// best). Unchanged.
// ---------------------------------------------------------------------------
__global__ __launch_bounds__(256) void agg_means(const uint_t* __restrict__ pk,
                                                 const int* __restrict__ offs,
                                                 const ushort_t* __restrict__ hold,
                                                 const float* __restrict__ inv,
                                                 ushort_t* __restrict__ M,
                                                 int lo, int rowsCap) {
    const int wv  = __builtin_amdgcn_readfirstlane(threadIdx.x >> 6);
    const int idx = blockIdx.x * 4 + wv;
    const int d   = lo + idx;
    const int lane = threadIdx.x & 63;
    const int beg = offs[d];
    const int end = offs[d + 1];
    const float4 w4 = ((const float4*)inv)[d];   // early s_load_dwordx4

    float a0x = 0.f, a0y = 0.f, a1x = 0.f, a1y = 0.f;
    float a2x = 0.f, a2y = 0.f, a3x = 0.f, a3y = 0.f;

    const uint_t* hold32 = (const uint_t*)hold;

    auto accs = [&](uint_t p, uint_t v, bool valid) {
        float x = bf2f(v & 0xffffu), y = bf2f(v >> 16);
        uint_t r = p >> 18;
        float m0 = (valid && r == 0u) ? 1.f : 0.f;
        float m1 = (valid && r == 1u) ? 1.f : 0.f;
        float m2 = (valid && r == 2u) ? 1.f : 0.f;
        float m3 = (valid && r == 3u) ? 1.f : 0.f;
        a0x += m0 * x;  a0y += m0 * y;
        a1x += m1 * x;  a1y += m1 * y;
        a2x += m2 * x;  a2y += m2 * y;
        a3x += m3 * x;  a3y += m3 * y;
    };

    for (int e = beg; e < end; e += 8) {
        const int last = end - 1;
        int a1i = (e + 1 < end) ? e + 1 : last;
        int a2i = (e + 2 < end) ? e + 2 : last;
        int a3i = (e + 3 < end) ? e + 3 : last;
        uint_t p0 = pk[e];
        uint_t p1 = pk[a1i];
        uint_t p2 = pk[a2i];
        uint_t p3 = pk[a3i];
        uint_t v0 = hold32[(size_t)(p0 & 0x3FFFFu) * 64 + lane];
        uint_t v1 = hold32[(size_t)(p1 & 0x3FFFFu) * 64 + lane];
        uint_t v2 = hold32[(size_t)(p2 & 0x3FFFFu) * 64 + lane];
        uint_t v3 = hold32[(size_t)(p3 & 0x3FFFFu) * 64 + lane];

        const bool hB = (e + 4 < end);   // wave-uniform -> scalar branch
        if (hB) {
            int b1i = (e + 5 < end) ? e + 5 : last;
            int b2i = (e + 6 < end) ? e + 6 : last;
            int b3i = (e + 7 < end) ? e + 7 : last;
            uint_t q0 = pk[e + 4];
            uint_t q1 = pk[b1i];
            uint_t q2 = pk[b2i];
            uint_t q3 = pk[b3i];
            uint_t u0 = hold32[(size_t)(q0 & 0x3FFFFu) * 64 + lane];
            uint_t u1 = hold32[(size_t)(q1 & 0x3FFFFu) * 64 + lane];
            uint_t u2 = hold32[(size_t)(q2 & 0x3FFFFu) * 64 + lane];
            uint_t u3 = hold32[(size_t)(q3 & 0x3FFFFu) * 64 + lane];
            accs(p0, v0, true);
            accs(p1, v1, true);
            accs(p2, v2, true);
            accs(p3, v3, true);
            accs(q0, u0, true);
            accs(q1, u1, e + 5 < end);
            accs(q2, u2, e + 6 < end);
            accs(q3, u3, e + 7 < end);
        } else {
            accs(p0, v0, true);
            accs(p1, v1, e + 1 < end);
            accs(p2, v2, e + 2 < end);
            accs(p3, v3, e + 3 < end);
        }
    }

    uint_t* P = (uint_t*)M;
    size_t planeU = (size_t)rowsCap * 64;
    size_t rowU = (size_t)idx * 64 + lane;
    P[rowU]              = f2bf(a0x * w4.x) | (f2bf(a0y * w4.x) << 16);
    P[planeU + rowU]     = f2bf(a1x * w4.y) | (f2bf(a1y * w4.y) << 16);
    P[2 * planeU + rowU] = f2bf(a2x * w4.z) | (f2bf(a2y * w4.z) << 16);
    P[3 * planeU + rowU] = f2bf(a3x * w4.w) | (f2bf(a3y * w4.w) << 16);
}

// ---------------------------------------------------------------------------
// Layer GEMM + LN + ReLU (+ optional fused head). hnew staged through LDS
// -> full-line stores (r25-verified). Unchanged.
// ---------------------------------------------------------------------------
template<bool HEAD>
__global__ __launch_bounds__(256) void layer_gemm_ln(
    const ushort_t* __restrict__ Mg,
    const ushort_t* __restrict__ hold,
    const short* __restrict__ Btg,       // [5][128 n][128 k] chunk-major
    const float* __restrict__ bconv,
    const float* __restrict__ lng,
    const float* __restrict__ lnb,
    ushort_t* __restrict__ hnew,
    const float* __restrict__ Wout,
    const float* __restrict__ bout,
    const float* __restrict__ basep,
    float* __restrict__ pred,
    int lo, int rowsCap) {
    __shared__ __align__(16) short As[64 * 128];       // 16 KB
    __shared__ __align__(16) short Bs[128 * 128];      // 32 KB
    __shared__ float lds_s[64][2], lds_q[64][2], lds_h[64][2];

    const int tid  = threadIdx.x;
    const int lane = tid & 63;
    const int l15  = lane & 15;
    const int q    = lane >> 4;
    const int wv   = tid >> 6;
    const int wr   = (wv >> 1) * 32;     // 2 row-bands of 32
    const int wc   = (wv & 1) * 64;      // 2 col-bands of 64
    const int blockRowL = blockIdx.x * 64;
    const size_t planeS = (size_t)rowsCap * 128;

    f32x4 acc[2][4];
    #pragma unroll
    for (int i = 0; i < 2; i++)
        #pragma unroll
        for (int j = 0; j < 4; j++) {
            acc[i][j][0] = 0.f; acc[i][j][1] = 0.f;
            acc[i][j][2] = 0.f; acc[i][j][3] = 0.f;
        }

    // per-lane source offset with XOR group swizzle (r12-verified).
    const int rloc = lane >> 4;
    const int gsw  = (lane & 15) ^ ((wv * 4 + rloc) & 15);
    const int lby  = (rloc << 8) + (gsw << 4);

    for (int kc = 0; kc < 5; kc++) {
        const char* asrc = (kc < 4)
            ? (const char*)(Mg + (size_t)kc * planeS + (size_t)blockRowL * 128)
            : (const char*)(hold + (size_t)(lo + blockRowL) * 128);
        const char* bsrc = (const char*)(Btg + (size_t)kc * 16384);
        __syncthreads();
        #pragma unroll
        for (int it = 0; it < 8; it++) {
            int off = it * 4096 + wv * 1024;
            if (it < 4) gl2lds16(asrc + off + lby, (char*)As + off);
            gl2lds16(bsrc + off + lby, (char*)Bs + off);
        }
        __syncthreads();

        #pragma unroll
        for (int kk = 0; kk < 4; kk++) {
            bf16x8 af[2], bfr[4];
            #pragma unroll
            for (int i = 0; i < 2; i++)
                af[i] = *(const bf16x8*)
                    &As[(wr + i * 16 + l15) * 128 + (((kk * 4 + q) ^ l15) << 3)];
            #pragma unroll
            for (int j = 0; j < 4; j++)
                bfr[j] = *(const bf16x8*)
                    &Bs[(wc + j * 16 + l15) * 128 + (((kk * 4 + q) ^ l15) << 3)];
            #pragma unroll
            for (int i = 0; i < 2; i++)
                #pragma unroll
                for (int j = 0; j < 4; j++)
                    acc[i][j] = __builtin_amdgcn_mfma_f32_16x16x32_bf16(
                        af[i], bfr[j], acc[i][j], 0, 0, 0);
        }
    }

    // ---- epilogue: + b_conv, LayerNorm, affine, ReLU (+ head dot) ----
    float bj[4], gj[4], bbj[4], wj[4];
    #pragma unroll
    for (int j = 0; j < 4; j++) {
        int col = wc + j * 16 + l15;
        bj[j]  = bconv[col];
        gj[j]  = lng[col];
        bbj[j] = lnb[col];
        if (HEAD) wj[j] = Wout[col];
    }
    #pragma unroll
    for (int i = 0; i < 2; i++)
        #pragma unroll
        for (int j = 0; j < 4; j++)
            #pragma unroll
            for (int r = 0; r < 4; r++) acc[i][j][r] += bj[j];

    float ps[2][4], pq[2][4];
    #pragma unroll
    for (int i = 0; i < 2; i++)
        #pragma unroll
        for (int r = 0; r < 4; r++) {
            float s = 0.f, qq = 0.f;
            #pragma unroll
            for (int j = 0; j < 4; j++) {
                float v = acc[i][j][r];
                s += v;
                qq += v * v;
            }
            ps[i][r] = s;
            pq[i][r] = qq;
        }
    #pragma unroll
    for (int m = 1; m <= 8; m <<= 1)
        #pragma unroll
        for (int i = 0; i < 2; i++)
            #pragma unroll
            for (int r = 0; r < 4; r++) {
                ps[i][r] += __shfl_xor(ps[i][r], m);
                pq[i][r] += __shfl_xor(pq[i][r], m);
            }

    if (l15 == 0) {
        #pragma unroll
        for (int i = 0; i < 2; i++)
            #pragma unroll
            for (int r = 0; r < 4; r++) {
                int row = wr + i * 16 + q * 4 + r;
                lds_s[row][wv & 1] = ps[i][r];
                lds_q[row][wv & 1] = pq[i][r];
            }
    }
    __syncthreads();   // also fences last Bs reads (K-loop done for all)

    ushort_t* Cs = (ushort_t*)Bs;        // 64*136*2 = 17408 B <= 32 KB
    float hs[2][4];
    #pragma unroll
    for (int i = 0; i < 2; i++)
        #pragma unroll
        for (int r = 0; r < 4; r++) {
            int row = wr + i * 16 + q * 4 + r;
            float sum = lds_s[row][0] + lds_s[row][1];
            float sq  = lds_q[row][0] + lds_q[row][1];
            float mu  = sum * (1.0f / 128.0f);
            float var = sq * (1.0f / 128.0f) - mu * mu;
            float rs  = rsqrtf(var + EPS_);
            float hd = 0.f;
            #pragma unroll
            for (int j = 0; j < 4; j++) {
                float v = (acc[i][j][r] - mu) * rs * gj[j] + bbj[j];
                v = fmaxf(v, 0.f);
                if (HEAD) hd += v * wj[j];
                else Cs[row * 136 + wc + j * 16 + l15] = (ushort_t)f2bf(v);
            }
            if (HEAD) hs[i][r] = hd;
        }

    if (!HEAD) {
        __syncthreads();
        #pragma unroll
        for (int k = 0; k < 4; k++) {
            int c = k * 256 + tid;        // 0..1023 uint4 chunks
            int row = c >> 4, seg = c & 15;
            uint4 v = *(const uint4*)&Cs[row * 136 + seg * 8];
            *(uint4*)&hnew[(size_t)(lo + blockRowL + row) * 128 + seg * 8] = v;
        }
    }

    if (HEAD) {
        #pragma unroll
        for (int m = 1; m <= 8; m <<= 1)
            #pragma unroll
            for (int i = 0; i < 2; i++)
                #pragma unroll
                for (int r = 0; r < 4; r++)
                    hs[i][r] += __shfl_xor(hs[i][r], m);
        if (l15 == 0) {
            #pragma unroll
            for (int i = 0; i < 2; i++)
                #pragma unroll
                for (int r = 0; r < 4; r++) {
                    int row = wr + i * 16 + q * 4 + r;
                    lds_h[row][wv & 1] = hs[i][r];
                }
        }
        __syncthreads();
        if (tid < 64)
            pred[lo + blockRowL + tid] =
                lds_h[tid][0] + lds_h[tid][1] + bout[0] + basep[0];
    }
}

// ---------------------------------------------------------------------------
extern "C" void kernel_launch(void* const* d_in, const int* in_sizes, int n_in,
                              void* d_out, int out_size, void* d_ws, size_t ws_size,
                              hipStream_t stream) {
    const float* x_a    = (const float*)d_in[0];
    const float* x_w    = (const float*)d_in[1];
    const int*   eidx   = (const int*)d_in[2];
    const int*   etype  = (const int*)d_in[3];
    const float* W_in_a = (const float*)d_in[4];
    const float* b_in_a = (const float*)d_in[5];
    const float* W_in_w = (const float*)d_in[6];
    const float* b_in_w = (const float*)d_in[7];
    const float* W_rel  = (const float*)d_in[8];
    const float* W_root = (const float*)d_in[9];
    const float* b_conv = (const float*)d_in[10];
    const float* ln_g   = (const float*)d_in[11];
    const float* ln_b   = (const float*)d_in[12];
    const float* W_out  = (const float*)d_in[13];
    const float* b_out  = (const float*)d_in[14];
    const float* base   = (const float*)d_in[15];

    const int* src  = eidx;
    const int* dstv = eidx + EE;

    // ---- workspace: hA placed LAST among persistents so layer-1's M can
    //      overlay [hA .. end] (hA is dead in layer 1). Layer-0's M uses
    //      [scratch .. end]. ----
    char* p = (char*)d_ws;
    auto alloc = [&](size_t bytes) {
        char* q = p;
        p += (bytes + 255) & ~(size_t)255;
        return q;
    };
    ushort_t* hB   = (ushort_t*)alloc((size_t)NN * 128 * 2);   // 67.1 MB
    float*    inv  = (float*)alloc((size_t)RR * NN * 4);       // 4.2 MB
    uint_t*   pk   = (uint_t*)alloc((size_t)EE * 4);           // 4.2 MB
    int*      offs = (int*)alloc((size_t)(NN + 1) * 4);        // 1.05 MB
    short*    wbuf = (short*)alloc((size_t)180224 * 2);        // 0.36 MB
    char*     hA_region = p;
    ushort_t* hA   = (ushort_t*)alloc((size_t)NN * 128 * 2);   // 67.1 MB
    char*     scratch = p;                                     // CSR tmp / M0
    uint_t*   cntp  = (uint_t*)alloc((size_t)NN * 64);         // padded, dead after CSR
    uchar_t*  rank  = (uchar_t*)alloc((size_t)EE);             // dead after CSR
    uint_t*   prefd = (uint_t*)alloc((size_t)NN * 4);          // dead after CSR
    int*      bsum  = (int*)alloc((size_t)1024 * 4);           // dead after CSR

    // layer-0 M: scratch..end (r26 chunk clamp REVERTED — it regressed:
    // +6 launches cost more than any M-retention gain; L3-retention theory
    // falsified twice, r19 + r26).
    size_t rem0 = (ws_size > (size_t)(scratch - (char*)d_ws))
                      ? (ws_size - (size_t)(scratch - (char*)d_ws)) : 0;
    int cap0 = (int)(rem0 / 1024);            // 1024 B per row (4 planes)
    if (cap0 > NN) cap0 = NN;
    cap0 &= ~127;
    if (cap0 == 0) cap0 = 128;
    size_t rem1 = (ws_size > (size_t)(hA_region - (char*)d_ws))
                      ? (ws_size - (size_t)(hA_region - (char*)d_ws)) : 0;
    int cap1 = (int)(rem1 / 1024);
    if (cap1 > NA_) cap1 = NA_;
    cap1 &= ~127;
    if (cap1 == 0) cap1 = 128;

    short* wt_ina = wbuf;
    short* wt_inw = wbuf + 8192;
    auto wt_layer = [&](int l) { return wbuf + 16384 + (size_t)l * 81920; };

    // ---- CSR + inv: memset, count, inv+scan1, bsum scan, add, place ----
    hipMemsetAsync(cntp, 0, (size_t)NN * 64, stream);
    count_edges<<<EE / 256, 256, 0, stream>>>(dstv, etype, cntp, rank);
    inv_scan1<<<NN / 256, 256, 0, stream>>>(cntp, inv, prefd, offs, bsum);
    scan_bsum<<<1, 256, 0, stream>>>(bsum);
    scan_add<<<NN / 256, 256, 0, stream>>>(offs, bsum);
    place_edges<<<EE / 1024, 256, 0, stream>>>(src, dstv, etype, rank, offs,
                                               prefd, pk);

    prep_weights<<<704, 256, 0, stream>>>(W_in_a, W_in_w, W_root, W_rel, wbuf);

    // ---- input projections: merged into one launch ----
    proj_gemm2<<<2 * (NA_ / 128), 256, 0, stream>>>(
        x_a, x_w, wt_ina, wt_inw, b_in_a, b_in_w, hA);

    // ---- layers; layer 2 only computes rows < NA and fuses the head ----
    ushort_t* hc = hA;
    ushort_t* hn = hB;
    for (int l = 0; l < 2; l++) {
        int Nout = (l == 0) ? NN : NA_;
        ushort_t* M = (l == 0) ? (ushort_t*)scratch : (ushort_t*)hA_region;
        int cap = (l == 0) ? cap0 : cap1;
        int nch = (Nout + cap - 1) / cap;
        int chunk = ((Nout / nch) + 127) & ~127;        // balanced, x128
        if (chunk > cap) chunk = cap;
        for (int lo = 0; lo < Nout; lo += chunk) {
            int cr = (Nout - lo < chunk) ? (Nout - lo) : chunk;
            agg_means<<<cr / 4, 256, 0, stream>>>(pk, offs, hc, inv, M, lo,
                                                  cap);
            if (l == 0)
                layer_gemm_ln<false><<<cr / 64, 256, 0, stream>>>(
                    M, hc, wt_layer(l), b_conv + l * 128, ln_g + l * 128,
                    ln_b + l * 128, hn, nullptr, nullptr, nullptr, nullptr,
                    lo, cap);
            else
                layer_gemm_ln<true><<<cr / 64, 256, 0, stream>>>(
                    M, hc, wt_layer(l), b_conv + l * 128, ln_g + l * 128,
                    ln_b + l * 128, nullptr, W_out, b_out, base,
                    (float*)d_out, lo, cap);
        }
        ushort_t* t = hc; hc = hn; hn = t;
    }
}